// Round 8
// baseline (420.193 us; speedup 1.0000x reference)
//
#include <hip/hip_runtime.h>
#include <stdint.h>

typedef unsigned short u16;
typedef __attribute__((ext_vector_type(8))) short short8;  // 8 bf16 (4 VGPRs)
typedef __attribute__((ext_vector_type(4))) float f32x4;   // MFMA C/D

#define B_ 8
#define T_ 4096
#define C_ 1024
#define H_ 128

#if __has_builtin(__builtin_amdgcn_exp2f)
#define EXP2(x) __builtin_amdgcn_exp2f(x)
#else
#define EXP2(x) exp2f(x)
#endif

__device__ __forceinline__ u16 f2bf(float f) {
  union { float f; uint32_t u; } v; v.f = f;
  uint32_t r = v.u + 0x7fffu + ((v.u >> 16) & 1u);  // RNE
  return (u16)(r >> 16);
}

// round-nearest (ties away) float->bf16: 1 add + 1 shift. Same 0.5ULP bound.
__device__ __forceinline__ u16 f2bf_rn(float f) {
  union { float f; uint32_t u; } v; v.f = f;
  return (u16)((v.u + 0x8000u) >> 16);
}

// async global->LDS DMA, 16B per lane. LDS dest is wave-uniform base +
// lane*16 (linear); global source is per-lane (we pre-swizzle it).
__device__ __forceinline__ void gl_lds16(const u16* g, u16* l) {
  __builtin_amdgcn_global_load_lds(
      (const __attribute__((address_space(1))) void*)g,
      (__attribute__((address_space(3))) void*)l, 16, 0, 0);
}

// ---------------------------------------------------------------------------
// W conversion: Wq|Wk|Wv fp32 -> Wb bf16 [384][1024].
// Wq pre-scaled by 1/sqrt(128) * log2(e) so attention uses exp2 directly.
// Also zeroes the 256 per-(batch,Q) finisher counters (runs before attn
// in stream order -> visible at attn dispatch).
// ---------------------------------------------------------------------------
__global__ __launch_bounds__(256) void wconv_kernel(
    const float* __restrict__ Wq, const float* __restrict__ Wk,
    const float* __restrict__ Wv, u16* __restrict__ Wb,
    uint32_t* __restrict__ cnt) {
  if (blockIdx.x == 0) cnt[threadIdx.x] = 0u;   // 256 counters = 8 b x 32 Q
  int g = (blockIdx.x * 256 + threadIdx.x) * 8;
  int head = g >> 17;
  int off  = g & 131071;
  const float* W = (head == 0) ? Wq : (head == 1) ? Wk : Wv;
  float s = (head == 0) ? 0.12751743342f : 1.0f;   // (1/sqrt(128))*log2(e)
  float4 a = *(const float4*)(W + off);
  float4 b = *(const float4*)(W + off + 4);
  u16 o[8] = {f2bf(a.x * s), f2bf(a.y * s), f2bf(a.z * s), f2bf(a.w * s),
              f2bf(b.x * s), f2bf(b.y * s), f2bf(b.z * s), f2bf(b.w * s)};
  *(uint4*)(Wb + g) = *(const uint4*)o;
}

// ---------------------------------------------------------------------------
// QKV projection v2: 512 blocks x 256 thr (4 waves), M=64 rows/block,
// N=384, K=1024, BK=64. Wave = 64 rows x 96 cols (acc[4][6] = 96 VGPR).
// W staged via global_load_lds into unpadded Wl[384][64] with chunk^(row&7)
// XOR swizzle; x reg-staged into padded Xl. Near x-read floor (~21 us).
// ---------------------------------------------------------------------------
__global__ __launch_bounds__(256, 2) void proj_kernel(
    const float* __restrict__ x, const u16* __restrict__ Wb,
    u16* __restrict__ qo, u16* __restrict__ ko, u16* __restrict__ vto) {
  __shared__ u16 Wl[384 * 64];   // 48 KB, DMA-staged, swizzled 16B chunks
  __shared__ u16 Xl[64 * 72];    // 9 KB, padded, reg-staged

  const int bm   = blockIdx.x;
  const int tid  = threadIdx.x;
  const int wave = tid >> 6;     // col-group: 96 cols each
  const int lane = tid & 63;
  const int m    = lane & 15;
  const int q4   = lane >> 4;

  f32x4 acc[4][6] = {};          // [row-strip][col-block]

  const int xrow = tid >> 2, xc16 = (tid & 3) * 16;
  // W DMA: call j stages rows wave*96 + j*8 + (lane>>3); row&7 = lane>>3.
  const u16* gW = Wb + (size_t)(wave * 96 + (lane >> 3)) * C_ +
                  (((lane & 7) ^ (lane >> 3)) << 3);
  const float* gX = x + (size_t)(bm * 64 + xrow) * C_ + xc16;

  for (int kc = 0; kc < C_; kc += 64) {
    __syncthreads();
    #pragma unroll
    for (int j = 0; j < 12; ++j)
      gl_lds16(gW + kc + (size_t)(j * 8) * C_, &Wl[(wave * 96 + j * 8) * 64]);
    {  // stage x[bm*64..+64)[kc..+64) fp32 -> bf16 (16 elems/thread)
      const float* xp = gX + kc;
      float4 a = *(const float4*)xp;
      float4 b = *(const float4*)(xp + 4);
      float4 c = *(const float4*)(xp + 8);
      float4 d = *(const float4*)(xp + 12);
      u16 o[16] = {f2bf_rn(a.x), f2bf_rn(a.y), f2bf_rn(a.z), f2bf_rn(a.w),
                   f2bf_rn(b.x), f2bf_rn(b.y), f2bf_rn(b.z), f2bf_rn(b.w),
                   f2bf_rn(c.x), f2bf_rn(c.y), f2bf_rn(c.z), f2bf_rn(c.w),
                   f2bf_rn(d.x), f2bf_rn(d.y), f2bf_rn(d.z), f2bf_rn(d.w)};
      *(uint4*)&Xl[xrow * 72 + xc16]     = *(const uint4*)&o[0];
      *(uint4*)&Xl[xrow * 72 + xc16 + 8] = *(const uint4*)&o[8];
    }
    __syncthreads();   // drains DMA vmcnt + LDS writes

    #pragma unroll
    for (int kb = 0; kb < 2; ++kb) {
      short8 af[4];
      #pragma unroll
      for (int s = 0; s < 4; ++s)
        af[s] = *(const short8*)&Xl[(s * 16 + m) * 72 + kb * 32 + q4 * 8];
      #pragma unroll
      for (int nb = 0; nb < 6; ++nb) {
        short8 bf = *(const short8*)&Wl[(wave * 96 + nb * 16 + m) * 64 +
                                        (((kb * 4 + q4) ^ (m & 7)) << 3)];
        #pragma unroll
        for (int s = 0; s < 4; ++s)
          acc[s][nb] =
              __builtin_amdgcn_mfma_f32_16x16x32_bf16(af[s], bf, acc[s][nb], 0, 0, 0);
      }
    }
  }

  #pragma unroll
  for (int s = 0; s < 4; ++s) {
    const int rowoff = s * 16 + q4 * 4;                // in [0,64)
    #pragma unroll
    for (int nb = 0; nb < 6; ++nb) {
      int col = wave * 96 + nb * 16 + m;   // 16-col tiles: head-uniform per nb
      f32x4 a = acc[s][nb];
      if (col < 128) {
        #pragma unroll
        for (int r = 0; r < 4; ++r)
          qo[(size_t)(bm * 64 + rowoff + r) * H_ + col] = f2bf(a[r]);
      } else if (col < 256) {
        #pragma unroll
        for (int r = 0; r < 4; ++r)
          ko[(size_t)(bm * 64 + rowoff + r) * H_ + (col - 128)] = f2bf(a[r]);
      } else {
        int b = bm >> 6;
        int t = (bm & 63) * 64 + rowoff;
        u16* vp = vto + (size_t)b * H_ * T_ + (size_t)(col - 256) * T_ + t;
        #pragma unroll
        for (int r = 0; r < 4; ++r) vp[r] = f2bf(a[r]);
      }
    }
  }
}

// ---------------------------------------------------------------------------
// Flash attention v6 = the PROVEN v3 structure (R3/R4, best measured)
// restored byte-for-byte: Q-tile 128 rows, dbuf K/V global_load_lds,
// chunk^(row&7) XOR swizzle, ONE barrier per kt iteration, LDS 80 KB.
// v4 (V-from-L2) and v5 (single-buffer, 2 barriers) both regressed and
// are abandoned.
// NEW (isolated to the epilogue): combine is fused as an atomic
// tail-finisher -- after writing its po/pl slot, each block threadfences
// and atomicAdds a per-(b,Q) counter; the last of the nc chunk-blocks
// combines (po slots L2/L3-warm) and writes out. No spinning; no
// separate combine dispatch.
// ---------------------------------------------------------------------------
__global__ __launch_bounds__(256, 2) void attn_kernel(
    const u16* __restrict__ q, const u16* __restrict__ k,
    const u16* __restrict__ vt, float* __restrict__ out,
    float* __restrict__ po, float* __restrict__ pl,
    uint32_t* __restrict__ cnt) {
  __shared__ u16 Kl[2][64 * 128];   // 2 x 16 KB, swizzled 16B chunks
  __shared__ u16 Vl[2][128 * 64];   // 2 x 16 KB, swizzled 16B chunks
  __shared__ u16 Pl[4][2][16 * 64]; // per-wave, per-strip P, swizzled; 16 KB
  __shared__ int fin;

  const int bid   = blockIdx.x;
  const int batch = bid & 7;        // == XCD id
  const int c     = bid >> 3;       // [0,80): heavy-first enumeration
  int Q, ck;
  if (c < 24)      { Q = 31 - c / 3;        ck = c % 3; }        // full, Q 24-31
  else if (c < 40) { Q = 23 - (c - 24) / 2; ck = (c - 24) & 1; } // full, Q 16-23
  else if (c < 48) { Q = 15 - (c - 40);     ck = 0; }            // full, Q 8-15
  else { int t = c - 48; int qm = 7 - (t >> 2);                  // tails, by len
         Q = qm + (t & 3) * 8; ck = Q >> 3; }
  const int k0   = ck * 16;
  const int kend = min(k0 + 16, 2 * Q + 2);
  const bool single = (Q < 8);

  const int tid  = threadIdx.x;
  const int wave = tid >> 6;
  const int lane = tid & 63;
  const int m    = lane & 15;
  const int q4   = lane >> 4;

  const size_t bbase = (size_t)batch * T_ * H_;
  const u16* vbase   = vt + (size_t)batch * H_ * T_;

  // Q fragments: 2 strips x 4 k-blocks (32 VGPR)
  short8 qf[2][4];
  #pragma unroll
  for (int si = 0; si < 2; ++si) {
    const u16* qp = q + bbase + (size_t)(Q * 128 + wave * 32 + si * 16 + m) * H_;
    #pragma unroll
    for (int kb = 0; kb < 4; ++kb)
      qf[si][kb] = *(const short8*)(qp + kb * 32 + q4 * 8);
  }

  // Per-lane pre-swizzled global source pointers (kt-independent part).
  const u16* gK[4];
  const u16* gV[4];
  #pragma unroll
  for (int j = 0; j < 4; ++j) {
    int r = wave * 16 + j * 4 + (lane >> 4);          // K row in [0,64)
    gK[j] = k + bbase + (size_t)r * H_ + (((lane & 15) ^ (r & 7)) << 3);
    int h = wave * 32 + j * 8 + (lane >> 3);          // V h-row in [0,128)
    gV[j] = vbase + (size_t)h * T_ + (((lane & 7) ^ (h & 7)) << 3);
  }

#define STAGE(bi, KT)                                                         \
  {                                                                           \
    u16* kd = &Kl[bi][wave * 16 * 128];                                       \
    const size_t ko_ = (size_t)(KT) * (64 * H_);                              \
    _Pragma("unroll") for (int j = 0; j < 4; ++j)                             \
        gl_lds16(gK[j] + ko_, kd + j * 4 * 128);                              \
    u16* vd = &Vl[bi][wave * 32 * 64];                                        \
    const size_t vo_ = (size_t)(KT) * 64;                                     \
    _Pragma("unroll") for (int j = 0; j < 4; ++j)                             \
        gl_lds16(gV[j] + vo_, vd + j * 8 * 64);                               \
  }

  float li[2][4] = {};              // per-lane partial row sums, 2 strips
  f32x4 o[2][8] = {};               // 64 VGPR accumulator
  const float NEGINF = -__builtin_inff();

  STAGE(0, k0);
  __syncthreads();
  int cur = 0;

  for (int kt = k0; kt < kend; ++kt) {
    if (kt + 1 < kend) STAGE(cur ^ 1, kt + 1);   // async, in flight all iter

    const bool diag = ((kt >> 1) == Q);

    // QK^T + exp fused per 16-col block; each kf read feeds BOTH strips.
    #pragma unroll
    for (int nb = 0; nb < 4; ++nb) {
      f32x4 a0 = {}, a1 = {};
      __builtin_amdgcn_s_setprio(1);
      #pragma unroll
      for (int kb = 0; kb < 4; ++kb) {
        short8 kf = *(const short8*)&Kl[cur][(nb * 16 + m) * 128 +
                                             (((kb * 4 + q4) ^ (m & 7)) << 3)];
        a0 = __builtin_amdgcn_mfma_f32_16x16x32_bf16(qf[0][kb], kf, a0, 0, 0, 0);
        a1 = __builtin_amdgcn_mfma_f32_16x16x32_bf16(qf[1][kb], kf, a1, 0, 0, 0);
      }
      __builtin_amdgcn_s_setprio(0);
      if (diag) {
        int key = ((kt & 1) << 6) + nb * 16 + m;
        #pragma unroll
        for (int r = 0; r < 4; ++r) {
          int row0 = wave * 32 + q4 * 4 + r;
          if (key > row0)      a0[r] = NEGINF;
          if (key > row0 + 16) a1[r] = NEGINF;
        }
      }
      #pragma unroll
      for (int r = 0; r < 4; ++r) {
        int rr = q4 * 4 + r;
        int cc = (((nb * 2 + (m >> 3)) ^ (rr & 7)) << 3) + (m & 7);
        float p0 = EXP2(a0[r]);
        li[0][r] += p0;
        Pl[wave][0][rr * 64 + cc] = f2bf_rn(p0);
        float p1 = EXP2(a1[r]);
        li[1][r] += p1;
        Pl[wave][1][rr * 64 + cc] = f2bf_rn(p1);
      }
    }

    __asm__ __volatile__("s_waitcnt lgkmcnt(0)" ::: "memory");
    __builtin_amdgcn_sched_barrier(0);

    // O += P V ; each vf read feeds BOTH strips
    __builtin_amdgcn_s_setprio(1);
    #pragma unroll
    for (int kb2 = 0; kb2 < 2; ++kb2) {
      short8 pf0 = *(const short8*)&Pl[wave][0][m * 64 +
                                   (((kb2 * 4 + q4) ^ (m & 7)) << 3)];
      short8 pf1 = *(const short8*)&Pl[wave][1][m * 64 +
                                   (((kb2 * 4 + q4) ^ (m & 7)) << 3)];
      #pragma unroll
      for (int nb = 0; nb < 8; ++nb) {
        short8 vf = *(const short8*)&Vl[cur][(nb * 16 + m) * 64 +
                                             (((kb2 * 4 + q4) ^ (m & 7)) << 3)];
        o[0][nb] = __builtin_amdgcn_mfma_f32_16x16x32_bf16(pf0, vf, o[0][nb], 0, 0, 0);
        o[1][nb] = __builtin_amdgcn_mfma_f32_16x16x32_bf16(pf1, vf, o[1][nb], 0, 0, 0);
      }
    }
    __builtin_amdgcn_s_setprio(0);

    if (kt + 1 < kend) {           // uniform per block
      __syncthreads();             // drains this wave's DMA (vmcnt) + lgkm
      cur ^= 1;
    }
  }

  // reduce li across the 16 lanes sharing q4 (once per task)
  #pragma unroll
  for (int si = 0; si < 2; ++si)
    #pragma unroll
    for (int r = 0; r < 4; ++r) {
      float t0 = li[si][r];
      t0 += __shfl_xor(t0, 1, 64);
      t0 += __shfl_xor(t0, 2, 64);
      t0 += __shfl_xor(t0, 4, 64);
      t0 += __shfl_xor(t0, 8, 64);
      li[si][r] = t0;
    }

  if (single) {
    #pragma unroll
    for (int si = 0; si < 2; ++si) {
      float* op = out + bbase + (size_t)(Q * 128 + wave * 32 + si * 16) * H_;
      #pragma unroll
      for (int nb = 0; nb < 8; ++nb)
        #pragma unroll
        for (int r = 0; r < 4; ++r)
          op[(q4 * 4 + r) * H_ + nb * 16 + m] = o[si][nb][r] / li[si][r];
    }
  } else {
    const int bq = batch * 32 + Q;
    const int nc = (Q >> 3) + 1;
    const size_t slot = (size_t)bq * 4 + ck;
    #pragma unroll
    for (int si = 0; si < 2; ++si) {
      float* pp = po + slot * 16384 + (size_t)(wave * 32 + si * 16) * 128;
      #pragma unroll
      for (int nb = 0; nb < 8; ++nb)
        #pragma unroll
        for (int r = 0; r < 4; ++r)
          pp[(q4 * 4 + r) * 128 + nb * 16 + m] = o[si][nb][r];
      if (m == 0) {
        #pragma unroll
        for (int r = 0; r < 4; ++r)
          pl[slot * 128 + wave * 32 + si * 16 + q4 * 4 + r] = li[si][r];
      }
    }

    // ---- atomic tail-finisher (fused combine) ----
    __threadfence();               // release this block's po/pl writes
    __syncthreads();               // all 256 threads fenced
    if (tid == 0) {
      uint32_t old = atomicAdd(&cnt[bq], 1u);   // device-scope RMW
      fin = (old == (uint32_t)(nc - 1));
    }
    __syncthreads();
    if (fin) {
      __threadfence();             // acquire: see other chunks' po/pl
      const int row   = tid >> 1;          // [0,128)
      const int halfo = (tid & 1) * 64;    // two half-rows per row
      const size_t sl0 = (size_t)bq * 4;
      float l = 0.f;
      for (int c2 = 0; c2 < nc; ++c2)
        l += pl[(sl0 + c2) * 128 + row];
      const float inv = 1.0f / l;
      const float* pp0 = po + sl0 * 16384 + (size_t)row * 128 + halfo;
      float* op = out + bbase + (size_t)(Q * 128 + row) * H_ + halfo;
      #pragma unroll 4
      for (int j = 0; j < 16; ++j) {
        float4 s = {0.f, 0.f, 0.f, 0.f};
        for (int c2 = 0; c2 < nc; ++c2) {
          float4 p = *(const float4*)(pp0 + (size_t)c2 * 16384 + j * 4);
          s.x += p.x; s.y += p.y; s.z += p.z; s.w += p.w;
        }
        float4 r2; r2.x = s.x * inv; r2.y = s.y * inv;
        r2.z = s.z * inv; r2.w = s.w * inv;
        *(float4*)(op + j * 4) = r2;
      }
    }
  }
}

// ---------------------------------------------------------------------------
extern "C" void kernel_launch(void* const* d_in, const int* in_sizes, int n_in,
                              void* d_out, int out_size, void* d_ws,
                              size_t ws_size, hipStream_t stream) {
  const float* x  = (const float*)d_in[0];
  const float* Wq = (const float*)d_in[1];
  const float* Wk = (const float*)d_in[2];
  const float* Wv = (const float*)d_in[3];

  const size_t n = (size_t)B_ * T_ * H_;   // 4,194,304
  u16* qb  = (u16*)d_ws;
  u16* kb  = qb + n;
  u16* vtb = kb + n;
  u16* Wbb = vtb + n;                       // 393,216 elems
  float* po = (float*)(Wbb + 393216);       // 1024 slots * 16384 f32 = 67 MB
  float* pl = po + (size_t)1024 * 16384;    // 131,072 fp32
  uint32_t* cnt = (uint32_t*)(pl + 131072); // 256 finisher counters
  // total ws usage ~93.7 MB

  wconv_kernel<<<dim3(192), dim3(256), 0, stream>>>(Wq, Wk, Wv, Wbb, cnt);
  proj_kernel<<<dim3(512), dim3(256), 0, stream>>>(x, Wbb, qb, kb, vtb);
  attn_kernel<<<dim3(640), dim3(256), 0, stream>>>(qb, kb, vtb, (float*)d_out,
                                                   po, pl, cnt);
}

// Round 9
// 400.189 us; speedup vs baseline: 1.0500x; 1.0500x over previous
//
#include <hip/hip_runtime.h>
#include <stdint.h>

typedef unsigned short u16;
typedef __attribute__((ext_vector_type(8))) short short8;  // 8 bf16 (4 VGPRs)
typedef __attribute__((ext_vector_type(4))) float f32x4;   // MFMA C/D

#define B_ 8
#define T_ 4096
#define C_ 1024
#define H_ 128

#if __has_builtin(__builtin_amdgcn_exp2f)
#define EXP2(x) __builtin_amdgcn_exp2f(x)
#else
#define EXP2(x) exp2f(x)
#endif

__device__ __forceinline__ u16 f2bf(float f) {
  union { float f; uint32_t u; } v; v.f = f;
  uint32_t r = v.u + 0x7fffu + ((v.u >> 16) & 1u);  // RNE
  return (u16)(r >> 16);
}

// round-nearest (ties away) float->bf16: 1 add + 1 shift. Same 0.5ULP bound.
__device__ __forceinline__ u16 f2bf_rn(float f) {
  union { float f; uint32_t u; } v; v.f = f;
  return (u16)((v.u + 0x8000u) >> 16);
}

// async global->LDS DMA, 16B per lane. LDS dest is wave-uniform base +
// lane*16 (linear); global source is per-lane (we pre-swizzle it).
__device__ __forceinline__ void gl_lds16(const u16* g, u16* l) {
  __builtin_amdgcn_global_load_lds(
      (const __attribute__((address_space(1))) void*)g,
      (__attribute__((address_space(3))) void*)l, 16, 0, 0);
}

// ---------------------------------------------------------------------------
// W conversion: Wq|Wk|Wv fp32 -> Wb bf16 [384][1024].
// Wq pre-scaled by 1/sqrt(128) * log2(e) so attention uses exp2 directly.
// Also zeroes the 256 per-(batch,Q) finisher counters (runs before attn
// in stream order -> visible at attn dispatch).
// ---------------------------------------------------------------------------
__global__ __launch_bounds__(256) void wconv_kernel(
    const float* __restrict__ Wq, const float* __restrict__ Wk,
    const float* __restrict__ Wv, u16* __restrict__ Wb,
    uint32_t* __restrict__ cnt) {
  if (blockIdx.x == 0) cnt[threadIdx.x] = 0u;   // 256 counters = 8 b x 32 Q
  int g = (blockIdx.x * 256 + threadIdx.x) * 8;
  int head = g >> 17;
  int off  = g & 131071;
  const float* W = (head == 0) ? Wq : (head == 1) ? Wk : Wv;
  float s = (head == 0) ? 0.12751743342f : 1.0f;   // (1/sqrt(128))*log2(e)
  float4 a = *(const float4*)(W + off);
  float4 b = *(const float4*)(W + off + 4);
  u16 o[8] = {f2bf(a.x * s), f2bf(a.y * s), f2bf(a.z * s), f2bf(a.w * s),
              f2bf(b.x * s), f2bf(b.y * s), f2bf(b.z * s), f2bf(b.w * s)};
  *(uint4*)(Wb + g) = *(const uint4*)o;
}

// ---------------------------------------------------------------------------
// QKV projection v2: 512 blocks x 256 thr (4 waves), M=64 rows/block,
// N=384, K=1024, BK=64. Wave = 64 rows x 96 cols (acc[4][6] = 96 VGPR).
// W staged via global_load_lds into unpadded Wl[384][64] with chunk^(row&7)
// XOR swizzle; x reg-staged into padded Xl. Near x-read floor (~21 us).
// ---------------------------------------------------------------------------
__global__ __launch_bounds__(256, 2) void proj_kernel(
    const float* __restrict__ x, const u16* __restrict__ Wb,
    u16* __restrict__ qo, u16* __restrict__ ko, u16* __restrict__ vto) {
  __shared__ u16 Wl[384 * 64];   // 48 KB, DMA-staged, swizzled 16B chunks
  __shared__ u16 Xl[64 * 72];    // 9 KB, padded, reg-staged

  const int bm   = blockIdx.x;
  const int tid  = threadIdx.x;
  const int wave = tid >> 6;     // col-group: 96 cols each
  const int lane = tid & 63;
  const int m    = lane & 15;
  const int q4   = lane >> 4;

  f32x4 acc[4][6] = {};          // [row-strip][col-block]

  const int xrow = tid >> 2, xc16 = (tid & 3) * 16;
  // W DMA: call j stages rows wave*96 + j*8 + (lane>>3); row&7 = lane>>3.
  const u16* gW = Wb + (size_t)(wave * 96 + (lane >> 3)) * C_ +
                  (((lane & 7) ^ (lane >> 3)) << 3);
  const float* gX = x + (size_t)(bm * 64 + xrow) * C_ + xc16;

  for (int kc = 0; kc < C_; kc += 64) {
    __syncthreads();
    #pragma unroll
    for (int j = 0; j < 12; ++j)
      gl_lds16(gW + kc + (size_t)(j * 8) * C_, &Wl[(wave * 96 + j * 8) * 64]);
    {  // stage x[bm*64..+64)[kc..+64) fp32 -> bf16 (16 elems/thread)
      const float* xp = gX + kc;
      float4 a = *(const float4*)xp;
      float4 b = *(const float4*)(xp + 4);
      float4 c = *(const float4*)(xp + 8);
      float4 d = *(const float4*)(xp + 12);
      u16 o[16] = {f2bf_rn(a.x), f2bf_rn(a.y), f2bf_rn(a.z), f2bf_rn(a.w),
                   f2bf_rn(b.x), f2bf_rn(b.y), f2bf_rn(b.z), f2bf_rn(b.w),
                   f2bf_rn(c.x), f2bf_rn(c.y), f2bf_rn(c.z), f2bf_rn(c.w),
                   f2bf_rn(d.x), f2bf_rn(d.y), f2bf_rn(d.z), f2bf_rn(d.w)};
      *(uint4*)&Xl[xrow * 72 + xc16]     = *(const uint4*)&o[0];
      *(uint4*)&Xl[xrow * 72 + xc16 + 8] = *(const uint4*)&o[8];
    }
    __syncthreads();   // drains DMA vmcnt + LDS writes

    #pragma unroll
    for (int kb = 0; kb < 2; ++kb) {
      short8 af[4];
      #pragma unroll
      for (int s = 0; s < 4; ++s)
        af[s] = *(const short8*)&Xl[(s * 16 + m) * 72 + kb * 32 + q4 * 8];
      #pragma unroll
      for (int nb = 0; nb < 6; ++nb) {
        short8 bf = *(const short8*)&Wl[(wave * 96 + nb * 16 + m) * 64 +
                                        (((kb * 4 + q4) ^ (m & 7)) << 3)];
        #pragma unroll
        for (int s = 0; s < 4; ++s)
          acc[s][nb] =
              __builtin_amdgcn_mfma_f32_16x16x32_bf16(af[s], bf, acc[s][nb], 0, 0, 0);
      }
    }
  }

  #pragma unroll
  for (int s = 0; s < 4; ++s) {
    const int rowoff = s * 16 + q4 * 4;                // in [0,64)
    #pragma unroll
    for (int nb = 0; nb < 6; ++nb) {
      int col = wave * 96 + nb * 16 + m;   // 16-col tiles: head-uniform per nb
      f32x4 a = acc[s][nb];
      if (col < 128) {
        #pragma unroll
        for (int r = 0; r < 4; ++r)
          qo[(size_t)(bm * 64 + rowoff + r) * H_ + col] = f2bf(a[r]);
      } else if (col < 256) {
        #pragma unroll
        for (int r = 0; r < 4; ++r)
          ko[(size_t)(bm * 64 + rowoff + r) * H_ + (col - 128)] = f2bf(a[r]);
      } else {
        int b = bm >> 6;
        int t = (bm & 63) * 64 + rowoff;
        u16* vp = vto + (size_t)b * H_ * T_ + (size_t)(col - 256) * T_ + t;
        #pragma unroll
        for (int r = 0; r < 4; ++r) vp[r] = f2bf(a[r]);
      }
    }
  }
}

// ---------------------------------------------------------------------------
// Flash attention v7 = v6 with the LDS-quantum bug fixed.
// R8 post-mortem: the dedicated `__shared__ int fin` padded LDS from
// exactly 81920 B to 82432 B -> 2 blocks/CU dropped to 1 (occupancy 21->9%,
// attn 61->208 us). v7 parks the finisher flag INSIDE Pl (dead storage in
// the epilogue; ordered by the __syncthreads before the flag write), so
// LDS is exactly 80 KB again -> 2 blocks/CU.
// Everything else: proven v3 loop (dbuf K/V DMA, XOR swizzle, one barrier
// per kt) + atomic tail-finisher replacing the combine dispatch.
// ---------------------------------------------------------------------------
__global__ __launch_bounds__(256, 2) void attn_kernel(
    const u16* __restrict__ q, const u16* __restrict__ k,
    const u16* __restrict__ vt, float* __restrict__ out,
    float* __restrict__ po, float* __restrict__ pl,
    uint32_t* __restrict__ cnt) {
  __shared__ u16 Kl[2][64 * 128];   // 2 x 16 KB, swizzled 16B chunks
  __shared__ u16 Vl[2][128 * 64];   // 2 x 16 KB, swizzled 16B chunks
  __shared__ u16 Pl[4][2][16 * 64]; // per-wave, per-strip P, swizzled; 16 KB
  // total LDS: exactly 81920 B -> 2 blocks/CU. Do NOT add shared vars.

  const int bid   = blockIdx.x;
  const int batch = bid & 7;        // == XCD id
  const int c     = bid >> 3;       // [0,80): heavy-first enumeration
  int Q, ck;
  if (c < 24)      { Q = 31 - c / 3;        ck = c % 3; }        // full, Q 24-31
  else if (c < 40) { Q = 23 - (c - 24) / 2; ck = (c - 24) & 1; } // full, Q 16-23
  else if (c < 48) { Q = 15 - (c - 40);     ck = 0; }            // full, Q 8-15
  else { int t = c - 48; int qm = 7 - (t >> 2);                  // tails, by len
         Q = qm + (t & 3) * 8; ck = Q >> 3; }
  const int k0   = ck * 16;
  const int kend = min(k0 + 16, 2 * Q + 2);
  const bool single = (Q < 8);

  const int tid  = threadIdx.x;
  const int wave = tid >> 6;
  const int lane = tid & 63;
  const int m    = lane & 15;
  const int q4   = lane >> 4;

  const size_t bbase = (size_t)batch * T_ * H_;
  const u16* vbase   = vt + (size_t)batch * H_ * T_;

  // Q fragments: 2 strips x 4 k-blocks (32 VGPR)
  short8 qf[2][4];
  #pragma unroll
  for (int si = 0; si < 2; ++si) {
    const u16* qp = q + bbase + (size_t)(Q * 128 + wave * 32 + si * 16 + m) * H_;
    #pragma unroll
    for (int kb = 0; kb < 4; ++kb)
      qf[si][kb] = *(const short8*)(qp + kb * 32 + q4 * 8);
  }

  // Per-lane pre-swizzled global source pointers (kt-independent part).
  const u16* gK[4];
  const u16* gV[4];
  #pragma unroll
  for (int j = 0; j < 4; ++j) {
    int r = wave * 16 + j * 4 + (lane >> 4);          // K row in [0,64)
    gK[j] = k + bbase + (size_t)r * H_ + (((lane & 15) ^ (r & 7)) << 3);
    int h = wave * 32 + j * 8 + (lane >> 3);          // V h-row in [0,128)
    gV[j] = vbase + (size_t)h * T_ + (((lane & 7) ^ (h & 7)) << 3);
  }

#define STAGE(bi, KT)                                                         \
  {                                                                           \
    u16* kd = &Kl[bi][wave * 16 * 128];                                       \
    const size_t ko_ = (size_t)(KT) * (64 * H_);                              \
    _Pragma("unroll") for (int j = 0; j < 4; ++j)                             \
        gl_lds16(gK[j] + ko_, kd + j * 4 * 128);                              \
    u16* vd = &Vl[bi][wave * 32 * 64];                                        \
    const size_t vo_ = (size_t)(KT) * 64;                                     \
    _Pragma("unroll") for (int j = 0; j < 4; ++j)                             \
        gl_lds16(gV[j] + vo_, vd + j * 8 * 64);                               \
  }

  float li[2][4] = {};              // per-lane partial row sums, 2 strips
  f32x4 o[2][8] = {};               // 64 VGPR accumulator
  const float NEGINF = -__builtin_inff();

  STAGE(0, k0);
  __syncthreads();
  int cur = 0;

  for (int kt = k0; kt < kend; ++kt) {
    if (kt + 1 < kend) STAGE(cur ^ 1, kt + 1);   // async, in flight all iter

    const bool diag = ((kt >> 1) == Q);

    // QK^T + exp fused per 16-col block; each kf read feeds BOTH strips.
    #pragma unroll
    for (int nb = 0; nb < 4; ++nb) {
      f32x4 a0 = {}, a1 = {};
      __builtin_amdgcn_s_setprio(1);
      #pragma unroll
      for (int kb = 0; kb < 4; ++kb) {
        short8 kf = *(const short8*)&Kl[cur][(nb * 16 + m) * 128 +
                                             (((kb * 4 + q4) ^ (m & 7)) << 3)];
        a0 = __builtin_amdgcn_mfma_f32_16x16x32_bf16(qf[0][kb], kf, a0, 0, 0, 0);
        a1 = __builtin_amdgcn_mfma_f32_16x16x32_bf16(qf[1][kb], kf, a1, 0, 0, 0);
      }
      __builtin_amdgcn_s_setprio(0);
      if (diag) {
        int key = ((kt & 1) << 6) + nb * 16 + m;
        #pragma unroll
        for (int r = 0; r < 4; ++r) {
          int row0 = wave * 32 + q4 * 4 + r;
          if (key > row0)      a0[r] = NEGINF;
          if (key > row0 + 16) a1[r] = NEGINF;
        }
      }
      #pragma unroll
      for (int r = 0; r < 4; ++r) {
        int rr = q4 * 4 + r;
        int cc = (((nb * 2 + (m >> 3)) ^ (rr & 7)) << 3) + (m & 7);
        float p0 = EXP2(a0[r]);
        li[0][r] += p0;
        Pl[wave][0][rr * 64 + cc] = f2bf_rn(p0);
        float p1 = EXP2(a1[r]);
        li[1][r] += p1;
        Pl[wave][1][rr * 64 + cc] = f2bf_rn(p1);
      }
    }

    __asm__ __volatile__("s_waitcnt lgkmcnt(0)" ::: "memory");
    __builtin_amdgcn_sched_barrier(0);

    // O += P V ; each vf read feeds BOTH strips
    __builtin_amdgcn_s_setprio(1);
    #pragma unroll
    for (int kb2 = 0; kb2 < 2; ++kb2) {
      short8 pf0 = *(const short8*)&Pl[wave][0][m * 64 +
                                   (((kb2 * 4 + q4) ^ (m & 7)) << 3)];
      short8 pf1 = *(const short8*)&Pl[wave][1][m * 64 +
                                   (((kb2 * 4 + q4) ^ (m & 7)) << 3)];
      #pragma unroll
      for (int nb = 0; nb < 8; ++nb) {
        short8 vf = *(const short8*)&Vl[cur][(nb * 16 + m) * 64 +
                                             (((kb2 * 4 + q4) ^ (m & 7)) << 3)];
        o[0][nb] = __builtin_amdgcn_mfma_f32_16x16x32_bf16(pf0, vf, o[0][nb], 0, 0, 0);
        o[1][nb] = __builtin_amdgcn_mfma_f32_16x16x32_bf16(pf1, vf, o[1][nb], 0, 0, 0);
      }
    }
    __builtin_amdgcn_s_setprio(0);

    if (kt + 1 < kend) {           // uniform per block
      __syncthreads();             // drains this wave's DMA (vmcnt) + lgkm
      cur ^= 1;
    }
  }

  // reduce li across the 16 lanes sharing q4 (once per task)
  #pragma unroll
  for (int si = 0; si < 2; ++si)
    #pragma unroll
    for (int r = 0; r < 4; ++r) {
      float t0 = li[si][r];
      t0 += __shfl_xor(t0, 1, 64);
      t0 += __shfl_xor(t0, 2, 64);
      t0 += __shfl_xor(t0, 4, 64);
      t0 += __shfl_xor(t0, 8, 64);
      li[si][r] = t0;
    }

  if (single) {
    #pragma unroll
    for (int si = 0; si < 2; ++si) {
      float* op = out + bbase + (size_t)(Q * 128 + wave * 32 + si * 16) * H_;
      #pragma unroll
      for (int nb = 0; nb < 8; ++nb)
        #pragma unroll
        for (int r = 0; r < 4; ++r)
          op[(q4 * 4 + r) * H_ + nb * 16 + m] = o[si][nb][r] / li[si][r];
    }
  } else {
    const int bq = batch * 32 + Q;
    const int nc = (Q >> 3) + 1;
    const size_t slot = (size_t)bq * 4 + ck;
    #pragma unroll
    for (int si = 0; si < 2; ++si) {
      float* pp = po + slot * 16384 + (size_t)(wave * 32 + si * 16) * 128;
      #pragma unroll
      for (int nb = 0; nb < 8; ++nb)
        #pragma unroll
        for (int r = 0; r < 4; ++r)
          pp[(q4 * 4 + r) * 128 + nb * 16 + m] = o[si][nb][r];
      if (m == 0) {
        #pragma unroll
        for (int r = 0; r < 4; ++r)
          pl[slot * 128 + wave * 32 + si * 16 + q4 * 4 + r] = li[si][r];
      }
    }

    // ---- atomic tail-finisher (fused combine) ----
    // Flag lives in Pl (dead storage now); LDS stays exactly 80 KB.
    volatile int* finp = (volatile int*)&Pl[0][0][0];
    __threadfence();               // release this block's po/pl writes
    __syncthreads();               // all threads fenced; Pl reads done
    if (tid == 0) {
      uint32_t old = atomicAdd(&cnt[bq], 1u);   // device-scope RMW
      *finp = (old == (uint32_t)(nc - 1)) ? 1 : 0;
    }
    __syncthreads();
    if (*finp) {
      __threadfence();             // acquire: see other chunks' po/pl
      const int row   = tid >> 1;          // [0,128)
      const int halfo = (tid & 1) * 64;    // two half-rows per row
      const size_t sl0 = (size_t)bq * 4;
      float l = 0.f;
      for (int c2 = 0; c2 < nc; ++c2)
        l += pl[(sl0 + c2) * 128 + row];
      const float inv = 1.0f / l;
      const float* pp0 = po + sl0 * 16384 + (size_t)row * 128 + halfo;
      float* op = out + bbase + (size_t)(Q * 128 + row) * H_ + halfo;
      #pragma unroll 4
      for (int j = 0; j < 16; ++j) {
        float4 s = {0.f, 0.f, 0.f, 0.f};
        for (int c2 = 0; c2 < nc; ++c2) {
          float4 p = *(const float4*)(pp0 + (size_t)c2 * 16384 + j * 4);
          s.x += p.x; s.y += p.y; s.z += p.z; s.w += p.w;
        }
        float4 r2; r2.x = s.x * inv; r2.y = s.y * inv;
        r2.z = s.z * inv; r2.w = s.w * inv;
        *(float4*)(op + j * 4) = r2;
      }
    }
  }
}

// ---------------------------------------------------------------------------
extern "C" void kernel_launch(void* const* d_in, const int* in_sizes, int n_in,
                              void* d_out, int out_size, void* d_ws,
                              size_t ws_size, hipStream_t stream) {
  const float* x  = (const float*)d_in[0];
  const float* Wq = (const float*)d_in[1];
  const float* Wk = (const float*)d_in[2];
  const float* Wv = (const float*)d_in[3];

  const size_t n = (size_t)B_ * T_ * H_;   // 4,194,304
  u16* qb  = (u16*)d_ws;
  u16* kb  = qb + n;
  u16* vtb = kb + n;
  u16* Wbb = vtb + n;                       // 393,216 elems
  float* po = (float*)(Wbb + 393216);       // 1024 slots * 16384 f32 = 67 MB
  float* pl = po + (size_t)1024 * 16384;    // 131,072 fp32
  uint32_t* cnt = (uint32_t*)(pl + 131072); // 256 finisher counters
  // total ws usage ~93.7 MB

  wconv_kernel<<<dim3(192), dim3(256), 0, stream>>>(Wq, Wk, Wv, Wbb, cnt);
  proj_kernel<<<dim3(512), dim3(256), 0, stream>>>(x, Wbb, qb, kb, vtb);
  attn_kernel<<<dim3(640), dim3(256), 0, stream>>>(qb, kb, vtb, (float*)d_out,
                                                   po, pl, cnt);
}

// Round 10
// 280.754 us; speedup vs baseline: 1.4967x; 1.4254x over previous
//
#include <hip/hip_runtime.h>
#include <stdint.h>

typedef unsigned short u16;
typedef __attribute__((ext_vector_type(8))) short short8;  // 8 bf16 (4 VGPRs)
typedef __attribute__((ext_vector_type(4))) float f32x4;   // MFMA C/D

#define B_ 8
#define T_ 4096
#define C_ 1024
#define H_ 128

#if __has_builtin(__builtin_amdgcn_exp2f)
#define EXP2(x) __builtin_amdgcn_exp2f(x)
#else
#define EXP2(x) exp2f(x)
#endif

__device__ __forceinline__ u16 f2bf(float f) {
  union { float f; uint32_t u; } v; v.f = f;
  uint32_t r = v.u + 0x7fffu + ((v.u >> 16) & 1u);  // RNE
  return (u16)(r >> 16);
}

// round-nearest (ties away) float->bf16: 1 add + 1 shift. Same 0.5ULP bound.
__device__ __forceinline__ u16 f2bf_rn(float f) {
  union { float f; uint32_t u; } v; v.f = f;
  return (u16)((v.u + 0x8000u) >> 16);
}

// async global->LDS DMA, 16B per lane. LDS dest is wave-uniform base +
// lane*16 (linear); global source is per-lane (we pre-swizzle it).
__device__ __forceinline__ void gl_lds16(const u16* g, u16* l) {
  __builtin_amdgcn_global_load_lds(
      (const __attribute__((address_space(1))) void*)g,
      (__attribute__((address_space(3))) void*)l, 16, 0, 0);
}

// ---------------------------------------------------------------------------
// W conversion: Wq|Wk|Wv fp32 -> Wb bf16 [384][1024].
// Wq pre-scaled by 1/sqrt(128) * log2(e) so attention uses exp2 directly.
// ---------------------------------------------------------------------------
__global__ __launch_bounds__(256) void wconv_kernel(
    const float* __restrict__ Wq, const float* __restrict__ Wk,
    const float* __restrict__ Wv, u16* __restrict__ Wb) {
  int g = (blockIdx.x * 256 + threadIdx.x) * 8;
  int head = g >> 17;
  int off  = g & 131071;
  const float* W = (head == 0) ? Wq : (head == 1) ? Wk : Wv;
  float s = (head == 0) ? 0.12751743342f : 1.0f;   // (1/sqrt(128))*log2(e)
  float4 a = *(const float4*)(W + off);
  float4 b = *(const float4*)(W + off + 4);
  u16 o[8] = {f2bf(a.x * s), f2bf(a.y * s), f2bf(a.z * s), f2bf(a.w * s),
              f2bf(b.x * s), f2bf(b.y * s), f2bf(b.z * s), f2bf(b.w * s)};
  *(uint4*)(Wb + g) = *(const uint4*)o;
}

// ---------------------------------------------------------------------------
// QKV projection v2: 512 blocks x 256 thr (4 waves), M=64 rows/block,
// N=384, K=1024, BK=64. Wave = 64 rows x 96 cols (acc[4][6] = 96 VGPR).
// W staged via global_load_lds into unpadded Wl[384][64] with chunk^(row&7)
// XOR swizzle; x reg-staged into padded Xl. Near x-read floor (~21 us).
// ---------------------------------------------------------------------------
__global__ __launch_bounds__(256, 2) void proj_kernel(
    const float* __restrict__ x, const u16* __restrict__ Wb,
    u16* __restrict__ qo, u16* __restrict__ ko, u16* __restrict__ vto) {
  __shared__ u16 Wl[384 * 64];   // 48 KB, DMA-staged, swizzled 16B chunks
  __shared__ u16 Xl[64 * 72];    // 9 KB, padded, reg-staged

  const int bm   = blockIdx.x;
  const int tid  = threadIdx.x;
  const int wave = tid >> 6;     // col-group: 96 cols each
  const int lane = tid & 63;
  const int m    = lane & 15;
  const int q4   = lane >> 4;

  f32x4 acc[4][6] = {};          // [row-strip][col-block]

  const int xrow = tid >> 2, xc16 = (tid & 3) * 16;
  // W DMA: call j stages rows wave*96 + j*8 + (lane>>3); row&7 = lane>>3.
  const u16* gW = Wb + (size_t)(wave * 96 + (lane >> 3)) * C_ +
                  (((lane & 7) ^ (lane >> 3)) << 3);
  const float* gX = x + (size_t)(bm * 64 + xrow) * C_ + xc16;

  for (int kc = 0; kc < C_; kc += 64) {
    __syncthreads();
    #pragma unroll
    for (int j = 0; j < 12; ++j)
      gl_lds16(gW + kc + (size_t)(j * 8) * C_, &Wl[(wave * 96 + j * 8) * 64]);
    {  // stage x[bm*64..+64)[kc..+64) fp32 -> bf16 (16 elems/thread)
      const float* xp = gX + kc;
      float4 a = *(const float4*)xp;
      float4 b = *(const float4*)(xp + 4);
      float4 c = *(const float4*)(xp + 8);
      float4 d = *(const float4*)(xp + 12);
      u16 o[16] = {f2bf_rn(a.x), f2bf_rn(a.y), f2bf_rn(a.z), f2bf_rn(a.w),
                   f2bf_rn(b.x), f2bf_rn(b.y), f2bf_rn(b.z), f2bf_rn(b.w),
                   f2bf_rn(c.x), f2bf_rn(c.y), f2bf_rn(c.z), f2bf_rn(c.w),
                   f2bf_rn(d.x), f2bf_rn(d.y), f2bf_rn(d.z), f2bf_rn(d.w)};
      *(uint4*)&Xl[xrow * 72 + xc16]     = *(const uint4*)&o[0];
      *(uint4*)&Xl[xrow * 72 + xc16 + 8] = *(const uint4*)&o[8];
    }
    __syncthreads();   // drains DMA vmcnt + LDS writes

    #pragma unroll
    for (int kb = 0; kb < 2; ++kb) {
      short8 af[4];
      #pragma unroll
      for (int s = 0; s < 4; ++s)
        af[s] = *(const short8*)&Xl[(s * 16 + m) * 72 + kb * 32 + q4 * 8];
      #pragma unroll
      for (int nb = 0; nb < 6; ++nb) {
        short8 bf = *(const short8*)&Wl[(wave * 96 + nb * 16 + m) * 64 +
                                        (((kb * 4 + q4) ^ (m & 7)) << 3)];
        #pragma unroll
        for (int s = 0; s < 4; ++s)
          acc[s][nb] =
              __builtin_amdgcn_mfma_f32_16x16x32_bf16(af[s], bf, acc[s][nb], 0, 0, 0);
      }
    }
  }

  #pragma unroll
  for (int s = 0; s < 4; ++s) {
    const int rowoff = s * 16 + q4 * 4;                // in [0,64)
    #pragma unroll
    for (int nb = 0; nb < 6; ++nb) {
      int col = wave * 96 + nb * 16 + m;   // 16-col tiles: head-uniform per nb
      f32x4 a = acc[s][nb];
      if (col < 128) {
        #pragma unroll
        for (int r = 0; r < 4; ++r)
          qo[(size_t)(bm * 64 + rowoff + r) * H_ + col] = f2bf(a[r]);
      } else if (col < 256) {
        #pragma unroll
        for (int r = 0; r < 4; ++r)
          ko[(size_t)(bm * 64 + rowoff + r) * H_ + (col - 128)] = f2bf(a[r]);
      } else {
        int b = bm >> 6;
        int t = (bm & 63) * 64 + rowoff;
        u16* vp = vto + (size_t)b * H_ * T_ + (size_t)(col - 256) * T_ + t;
        #pragma unroll
        for (int r = 0; r < 4; ++r) vp[r] = f2bf(a[r]);
      }
    }
  }
}

// ---------------------------------------------------------------------------
// Flash attention v3 (the verified optimum, R3/R4: total 277.9 us).
// Q-tile 128 rows/block (wave owns TWO 16-row strips); every K/V fragment
// read feeds two MFMAs. Task = (batch, Q[0..31], ck); 640 tasks heavy-first.
// K/V staged via global_load_lds, double-buffered, chunk^(row&7) XOR swizzle
// (linear LDS dest + pre-swizzled global src + same XOR on reads).
// ONE barrier per kt iteration. LDS exactly 80 KB -> 2 blocks/CU.
//
// Session verdict (R4-R9): v4 L2-direct-V 131us (exposed global latency in
// PV), v5 single-buffer 97us (extra barrier, no occupancy gain), v6 208us
// (+4B shared var broke the 80KB LDS quantum), v7 fence-finisher 187us
// (__threadfence = buffer_wbl2/inv on XCD-noncoherent L2 -> evicts pinned
// K/V, serializes DMA). All reverted. Separate combine dispatch retained.
// ---------------------------------------------------------------------------
__global__ __launch_bounds__(256, 2) void attn_kernel(
    const u16* __restrict__ q, const u16* __restrict__ k,
    const u16* __restrict__ vt, float* __restrict__ out,
    float* __restrict__ po, float* __restrict__ pl) {
  __shared__ u16 Kl[2][64 * 128];   // 2 x 16 KB, swizzled 16B chunks
  __shared__ u16 Vl[2][128 * 64];   // 2 x 16 KB, swizzled 16B chunks
  __shared__ u16 Pl[4][2][16 * 64]; // per-wave, per-strip P, swizzled; 16 KB

  const int bid   = blockIdx.x;
  const int batch = bid & 7;        // == XCD id
  const int c     = bid >> 3;       // [0,80): heavy-first enumeration
  int Q, ck;
  if (c < 24)      { Q = 31 - c / 3;        ck = c % 3; }        // full, Q 24-31
  else if (c < 40) { Q = 23 - (c - 24) / 2; ck = (c - 24) & 1; } // full, Q 16-23
  else if (c < 48) { Q = 15 - (c - 40);     ck = 0; }            // full, Q 8-15
  else { int t = c - 48; int qm = 7 - (t >> 2);                  // tails, by len
         Q = qm + (t & 3) * 8; ck = Q >> 3; }
  const int k0   = ck * 16;
  const int kend = min(k0 + 16, 2 * Q + 2);
  const bool single = (Q < 8);

  const int tid  = threadIdx.x;
  const int wave = tid >> 6;
  const int lane = tid & 63;
  const int m    = lane & 15;
  const int q4   = lane >> 4;

  const size_t bbase = (size_t)batch * T_ * H_;
  const u16* vbase   = vt + (size_t)batch * H_ * T_;

  // Q fragments: 2 strips x 4 k-blocks (32 VGPR)
  short8 qf[2][4];
  #pragma unroll
  for (int si = 0; si < 2; ++si) {
    const u16* qp = q + bbase + (size_t)(Q * 128 + wave * 32 + si * 16 + m) * H_;
    #pragma unroll
    for (int kb = 0; kb < 4; ++kb)
      qf[si][kb] = *(const short8*)(qp + kb * 32 + q4 * 8);
  }

  // Per-lane pre-swizzled global source pointers (kt-independent part).
  const u16* gK[4];
  const u16* gV[4];
  #pragma unroll
  for (int j = 0; j < 4; ++j) {
    int r = wave * 16 + j * 4 + (lane >> 4);          // K row in [0,64)
    gK[j] = k + bbase + (size_t)r * H_ + (((lane & 15) ^ (r & 7)) << 3);
    int h = wave * 32 + j * 8 + (lane >> 3);          // V h-row in [0,128)
    gV[j] = vbase + (size_t)h * T_ + (((lane & 7) ^ (h & 7)) << 3);
  }

#define STAGE(bi, KT)                                                         \
  {                                                                           \
    u16* kd = &Kl[bi][wave * 16 * 128];                                       \
    const size_t ko_ = (size_t)(KT) * (64 * H_);                              \
    _Pragma("unroll") for (int j = 0; j < 4; ++j)                             \
        gl_lds16(gK[j] + ko_, kd + j * 4 * 128);                              \
    u16* vd = &Vl[bi][wave * 32 * 64];                                        \
    const size_t vo_ = (size_t)(KT) * 64;                                     \
    _Pragma("unroll") for (int j = 0; j < 4; ++j)                             \
        gl_lds16(gV[j] + vo_, vd + j * 8 * 64);                               \
  }

  float li[2][4] = {};              // per-lane partial row sums, 2 strips
  f32x4 o[2][8] = {};               // 64 VGPR accumulator
  const float NEGINF = -__builtin_inff();

  STAGE(0, k0);
  __syncthreads();
  int cur = 0;

  for (int kt = k0; kt < kend; ++kt) {
    if (kt + 1 < kend) STAGE(cur ^ 1, kt + 1);   // async, in flight all iter

    const bool diag = ((kt >> 1) == Q);

    // QK^T + exp fused per 16-col block; each kf read feeds BOTH strips.
    #pragma unroll
    for (int nb = 0; nb < 4; ++nb) {
      f32x4 a0 = {}, a1 = {};
      __builtin_amdgcn_s_setprio(1);
      #pragma unroll
      for (int kb = 0; kb < 4; ++kb) {
        short8 kf = *(const short8*)&Kl[cur][(nb * 16 + m) * 128 +
                                             (((kb * 4 + q4) ^ (m & 7)) << 3)];
        a0 = __builtin_amdgcn_mfma_f32_16x16x32_bf16(qf[0][kb], kf, a0, 0, 0, 0);
        a1 = __builtin_amdgcn_mfma_f32_16x16x32_bf16(qf[1][kb], kf, a1, 0, 0, 0);
      }
      __builtin_amdgcn_s_setprio(0);
      if (diag) {
        int key = ((kt & 1) << 6) + nb * 16 + m;
        #pragma unroll
        for (int r = 0; r < 4; ++r) {
          int row0 = wave * 32 + q4 * 4 + r;
          if (key > row0)      a0[r] = NEGINF;
          if (key > row0 + 16) a1[r] = NEGINF;
        }
      }
      #pragma unroll
      for (int r = 0; r < 4; ++r) {
        int rr = q4 * 4 + r;
        int cc = (((nb * 2 + (m >> 3)) ^ (rr & 7)) << 3) + (m & 7);
        float p0 = EXP2(a0[r]);
        li[0][r] += p0;
        Pl[wave][0][rr * 64 + cc] = f2bf_rn(p0);
        float p1 = EXP2(a1[r]);
        li[1][r] += p1;
        Pl[wave][1][rr * 64 + cc] = f2bf_rn(p1);
      }
    }

    __asm__ __volatile__("s_waitcnt lgkmcnt(0)" ::: "memory");
    __builtin_amdgcn_sched_barrier(0);

    // O += P V ; each vf read feeds BOTH strips
    __builtin_amdgcn_s_setprio(1);
    #pragma unroll
    for (int kb2 = 0; kb2 < 2; ++kb2) {
      short8 pf0 = *(const short8*)&Pl[wave][0][m * 64 +
                                   (((kb2 * 4 + q4) ^ (m & 7)) << 3)];
      short8 pf1 = *(const short8*)&Pl[wave][1][m * 64 +
                                   (((kb2 * 4 + q4) ^ (m & 7)) << 3)];
      #pragma unroll
      for (int nb = 0; nb < 8; ++nb) {
        short8 vf = *(const short8*)&Vl[cur][(nb * 16 + m) * 64 +
                                             (((kb2 * 4 + q4) ^ (m & 7)) << 3)];
        o[0][nb] = __builtin_amdgcn_mfma_f32_16x16x32_bf16(pf0, vf, o[0][nb], 0, 0, 0);
        o[1][nb] = __builtin_amdgcn_mfma_f32_16x16x32_bf16(pf1, vf, o[1][nb], 0, 0, 0);
      }
    }
    __builtin_amdgcn_s_setprio(0);

    if (kt + 1 < kend) {           // uniform per block
      __syncthreads();             // drains this wave's DMA (vmcnt) + lgkm
      cur ^= 1;
    }
  }

  // reduce li across the 16 lanes sharing q4 (once per task)
  #pragma unroll
  for (int si = 0; si < 2; ++si)
    #pragma unroll
    for (int r = 0; r < 4; ++r) {
      float t0 = li[si][r];
      t0 += __shfl_xor(t0, 1, 64);
      t0 += __shfl_xor(t0, 2, 64);
      t0 += __shfl_xor(t0, 4, 64);
      t0 += __shfl_xor(t0, 8, 64);
      li[si][r] = t0;
    }

  if (single) {
    #pragma unroll
    for (int si = 0; si < 2; ++si) {
      float* op = out + bbase + (size_t)(Q * 128 + wave * 32 + si * 16) * H_;
      #pragma unroll
      for (int nb = 0; nb < 8; ++nb)
        #pragma unroll
        for (int r = 0; r < 4; ++r)
          op[(q4 * 4 + r) * H_ + nb * 16 + m] = o[si][nb][r] / li[si][r];
    }
  } else {
    const size_t slot = (size_t)(batch * 32 + Q) * 4 + ck;
    #pragma unroll
    for (int si = 0; si < 2; ++si) {
      float* pp = po + slot * 16384 + (size_t)(wave * 32 + si * 16) * 128;
      #pragma unroll
      for (int nb = 0; nb < 8; ++nb)
        #pragma unroll
        for (int r = 0; r < 4; ++r)
          pp[(q4 * 4 + r) * 128 + nb * 16 + m] = o[si][nb][r];
      if (m == 0) {
        #pragma unroll
        for (int r = 0; r < 4; ++r)
          pl[slot * 128 + wave * 32 + si * 16 + q4 * 4 + r] = li[si][r];
      }
    }
  }
}

// ---------------------------------------------------------------------------
// Combine: out = sum_c o_c / sum_c l_c  (additive -- same implicit max=0)
// ---------------------------------------------------------------------------
__global__ __launch_bounds__(256) void combine_kernel(
    const float* __restrict__ po, const float* __restrict__ pl,
    float* __restrict__ out) {
  int gid = blockIdx.x * 256 + threadIdx.x;   // 1,048,576 threads
  int h4  = (gid & 31) * 4;
  int tt  = (gid >> 5) & 4095;
  int b   = gid >> 17;
  int Q   = tt >> 7, row = tt & 127;
  if (Q < 8) return;                          // written directly by attn
  int nc = (Q >> 3) + 1;
  float4 s = {0.f, 0.f, 0.f, 0.f};
  float l = 0.f;
  for (int ck = 0; ck < nc; ++ck) {
    size_t slot = (size_t)(b * 32 + Q) * 4 + ck;
    float4 p = *(const float4*)(po + slot * 16384 + row * 128 + h4);
    s.x += p.x; s.y += p.y; s.z += p.z; s.w += p.w;
    l += pl[slot * 128 + row];
  }
  float inv = 1.0f / l;
  float4 r; r.x = s.x * inv; r.y = s.y * inv; r.z = s.z * inv; r.w = s.w * inv;
  *(float4*)(out + ((size_t)b * T_ + tt) * H_ + h4) = r;
}

// ---------------------------------------------------------------------------
extern "C" void kernel_launch(void* const* d_in, const int* in_sizes, int n_in,
                              void* d_out, int out_size, void* d_ws,
                              size_t ws_size, hipStream_t stream) {
  const float* x  = (const float*)d_in[0];
  const float* Wq = (const float*)d_in[1];
  const float* Wk = (const float*)d_in[2];
  const float* Wv = (const float*)d_in[3];

  const size_t n = (size_t)B_ * T_ * H_;   // 4,194,304
  u16* qb  = (u16*)d_ws;
  u16* kb  = qb + n;
  u16* vtb = kb + n;
  u16* Wbb = vtb + n;                       // 393,216 elems
  float* po = (float*)(Wbb + 393216);       // 1024 slots * 16384 f32 = 67 MB
  float* pl = po + (size_t)1024 * 16384;    // 131,072 fp32
  // total ws usage ~93.6 MB

  wconv_kernel<<<dim3(192), dim3(256), 0, stream>>>(Wq, Wk, Wv, Wbb);
  proj_kernel<<<dim3(512), dim3(256), 0, stream>>>(x, Wbb, qb, kb, vtb);
  attn_kernel<<<dim3(640), dim3(256), 0, stream>>>(qb, kb, vtb, (float*)d_out, po, pl);
  combine_kernel<<<dim3(4096), dim3(256), 0, stream>>>(po, pl, (float*)d_out);
}